// Round 8
// baseline (133.816 us; speedup 1.0000x reference)
//
#include <hip/hip_runtime.h>
#include <cstdint>

// Problem constants: B=32, T=D=256, rows R = B*T = 8192, K = 256.
#define R_TOT 8192
#define KD    256
#define SLOT  ((size_t)R_TOT * KD)            // bytes per fp8 image (2,097,152)
// ws layout (bytes):  total ~4.8 MB (was 21.3 MB)
#define IVN_OFF  0                            // 64 f32: 1/frobenius-norm [ten][j]
#define ICN_OFF  256                          // 2*8192 f32: 1/col-norm [ten][j][s]
#define CSQ_OFF  (ICN_OFF + 65536)            // 8 tc-partials x 2*8192 f32 = 512 KB
#define MATS_OFF (CSQ_OFF + 524288)           // 2 fp8 images (Vq, Aq), permuted+swizzled, 4 MB

typedef float f32x4 __attribute__((ext_vector_type(4)));
typedef long  lx2   __attribute__((ext_vector_type(2)));   // 16B = 2 fp8 MFMA operands

__device__ __forceinline__ void glds16(const void* g, void* l){
  __builtin_amdgcn_global_load_lds((const __attribute__((address_space(1))) uint32_t*)g,
                                   (__attribute__((address_space(3))) uint32_t*)l, 16, 0, 0);
}

// Image byte layout per 256-B row r (k = 0..255):
//   t = k>>6, half = (k>>5)&1, kh = (k>>3)&3, lo = k&7
//   chunk q = t*4 + kh, stored at 16B slot (q ^ (r&15)), byte half*8 + lo.
// => one ds_read_b128 at slot ((t*4+kh) ^ (r&15)) yields fp8 MFMA fragments for
//    k-chunks 2t and 2t+1 at quad kh; XOR swizzle -> conflict-free (verified R7).
__global__ void cast_ns_k(const float* __restrict__ V, const float* __restrict__ A,
                          unsigned char* __restrict__ mats, float* __restrict__ csq){
  const int tc = blockIdx.x, j = blockIdx.y, ten = blockIdx.z;
  const int tid = threadIdx.x;
  const int g    = tid & 31;                 // d-chunk of 8 floats
  const int tsub = tid >> 5;                 // 0..7
  const int q    = ((g >> 3) << 2) | (g & 3);
  const int half = (g >> 2) & 1;
  const float* X = (ten ? A : V) + (size_t)j * 65536;
  unsigned char* M = mats + (size_t)ten * SLOT + (size_t)j * 65536;
  float cs[8];
  #pragma unroll
  for (int e = 0; e < 8; ++e) cs[e] = 0.f;
  #pragma unroll
  for (int tt = 0; tt < 4; ++tt){
    const int t = tc * 32 + tt * 8 + tsub;
    const float4 p0 = *(const float4*)(X + t * 256 + g * 8);
    const float4 p1 = *(const float4*)(X + t * 256 + g * 8 + 4);
    cs[0] += p0.x * p0.x; cs[1] += p0.y * p0.y; cs[2] += p0.z * p0.z; cs[3] += p0.w * p0.w;
    cs[4] += p1.x * p1.x; cs[5] += p1.y * p1.y; cs[6] += p1.z * p1.z; cs[7] += p1.w * p1.w;
    int d0 = __builtin_amdgcn_cvt_pk_fp8_f32(p0.x, p0.y, 0, false);
    d0     = __builtin_amdgcn_cvt_pk_fp8_f32(p0.z, p0.w, d0, true);
    int d1 = __builtin_amdgcn_cvt_pk_fp8_f32(p1.x, p1.y, 0, false);
    d1     = __builtin_amdgcn_cvt_pk_fp8_f32(p1.z, p1.w, d1, true);
    int2 o; o.x = d0; o.y = d1;
    *(int2*)(M + (size_t)t * 256 + (((q ^ (t & 15)) << 4) | (half << 3))) = o;
  }
  __shared__ float red[8][256];
  #pragma unroll
  for (int e = 0; e < 8; ++e) red[tsub][g * 8 + e] = cs[e];
  __syncthreads();
  float s = 0.f;
  #pragma unroll
  for (int gg = 0; gg < 8; ++gg) s += red[gg][tid];
  csq[(size_t)((tc * 2 + ten) * 32 + j) * 256 + tid] = s;
}

// Finish norms: sum 8 tc-partials; icn = rsqrt, ivn = rsqrt of row-sum. Grid (32, 2).
__global__ void nreduce_k(const float* __restrict__ csq, float* __restrict__ ivn,
                          float* __restrict__ icn){
  const int j = blockIdx.x, ten = blockIdx.y, s = threadIdx.x;
  float c = 0.f;
  #pragma unroll
  for (int tc = 0; tc < 8; ++tc)
    c += csq[(size_t)((tc * 2 + ten) * 32 + j) * 256 + s];
  icn[ten * 8192 + j * 256 + s] = rsqrtf(c + 1e-18f);
  __shared__ float red[256];
  red[s] = c; __syncthreads();
  for (int off = 128; off > 0; off >>= 1){
    if (s < off) red[s] += red[s + off];
    __syncthreads();
  }
  if (s == 0) ivn[ten * 32 + j] = rsqrtf(red[0] + 1e-18f);
}

// v8: BOTH directions in one block + fused log1p-combine + direct out store.
// Block tile 64 rows x 32 cols, 4 waves of 32x16; grid (8 sb, 128 rb) = 1024 blocks
// = exactly 4/CU (16 waves). Per dir: afr 32 VGPRs from swizzled global, B col tile
// 8KB x2 LDS dbuf via global_load_lds. No intermediate `part` buffer.
__global__ __launch_bounds__(256, 4) void gemm_both_k(const unsigned char* __restrict__ mats,
                                                      const float* __restrict__ ivn,
                                                      const float* __restrict__ icn,
                                                      float* __restrict__ out){
  __shared__ __align__(16) char smem[16384];          // 2 x 8KB B buffers; epilogue reuse
  const int tid  = threadIdx.x;
  const int lane = tid & 63;
  const int w    = tid >> 6;
  const int wm   = (w & 1) * 32;        // wave row offset in 64-row block tile
  const int wn   = (w >> 1) * 16;       // wave col offset in 32-col block tile
  const int wno  = wn << 8;             // byte offset of col group in LDS tile
  const int lm   = lane & 15;
  const int kh   = lane >> 4;           // 0..3
  const int s0   = blockIdx.x * 32;
  const int rb   = blockIdx.y;
  const int r0   = rb * 64;
  const int ib   = rb >> 2;             // batch index of this row tile (excluded diagonal)

  // ds_read addrs (dir/j-invariant): addr(t) = nl*256 + (((t*4+kh) ^ (nl&15))<<4),
  // nl = wn + lm; wn part is the uniform wno. Decompose XOR into bits 6-7:
  int a4[4];
  {
    const int base  = lm * 256 + ((kh ^ (lm & 3)) << 4);   // bits 6-7 clear
    const int base2 = base ^ ((lm >> 2) << 6);
    #pragma unroll
    for (int t = 0; t < 4; ++t) a4[t] = base2 ^ (t << 6);
  }

  f32x4 accd[2][2];                     // [dir][mi]
  #pragma unroll
  for (int d = 0; d < 2; ++d)
    #pragma unroll
    for (int mi = 0; mi < 2; ++mi)
      accd[d][mi] = f32x4{0.f, 0.f, 0.f, 0.f};

  #pragma unroll
  for (int dir = 0; dir < 2; ++dir){
    // dir0: rows Vq scaled by 1/|V_i|F, cols Aq by 1/colnorm(A_j); dir1 swapped.
    const unsigned char* rowmat = mats + (size_t)dir * SLOT;
    const unsigned char* colmat = mats + (size_t)(1 - dir) * SLOT;
    const float sivn = ivn[dir * 32 + ib] * 1.44269504088896340736f;  // * log2(e)
    const float* icnb = icn + (size_t)(1 - dir) * 8192 + s0 + wn + lm;

    // A-fragments: m = r0 + wm + mi*16 + lm; slot (t*4+kh) ^ (m&15), m&15 == lm.
    lx2 afr[2][4];
    #pragma unroll
    for (int mi = 0; mi < 2; ++mi){
      const unsigned char* rp = rowmat + (size_t)(r0 + wm + mi * 16 + lm) * 256;
      #pragma unroll
      for (int t = 0; t < 4; ++t)
        afr[mi][t] = *(const lx2*)(rp + (((((t << 2) | kh)) ^ lm) << 4));
    }
    #pragma unroll
    for (int mi = 0; mi < 2; ++mi)
      #pragma unroll
      for (int t = 0; t < 4; ++t)
        asm volatile("" : "+v"(afr[mi][t]));

    // Preload j(0) into buffer 0 (8 KB = 2 chunks/thread).
    {
      const int j0 = (ib == 0) ? 1 : 0;
      const unsigned char* src = colmat + ((size_t)j0 * 256 + s0) * 256;
      #pragma unroll
      for (int c = 0; c < 2; ++c)
        glds16(src + (size_t)(c * 256 + tid) * 16, smem + (c * 256 + w * 64) * 16);
    }
    __syncthreads();

    for (int jj = 0; jj < 31; ++jj){
      const int j = jj + (jj >= ib ? 1 : 0);
      if (jj < 30){
        const int jn = (jj + 1) + ((jj + 1) >= ib ? 1 : 0);
        const unsigned char* src = colmat + ((size_t)jn * 256 + s0) * 256;
        char* dst = smem + (((jj + 1) & 1) << 13);
        #pragma unroll
        for (int c = 0; c < 2; ++c)
          glds16(src + (size_t)(c * 256 + tid) * 16, dst + (c * 256 + w * 64) * 16);
      }

      const float csc = sivn * icnb[j * 256];   // this lane's column scale for block j

      const char* rbuf = smem + ((jj & 1) << 13);
      f32x4 S[2];
      S[0] = f32x4{0.f, 0.f, 0.f, 0.f};
      S[1] = f32x4{0.f, 0.f, 0.f, 0.f};

      #pragma unroll
      for (int t = 0; t < 4; ++t){
        lx2 b = *(const lx2*)(rbuf + a4[t] + wno);
        S[0] = __builtin_amdgcn_mfma_f32_16x16x32_fp8_fp8(afr[0][t][0], b[0], S[0], 0, 0, 0);
        S[1] = __builtin_amdgcn_mfma_f32_16x16x32_fp8_fp8(afr[1][t][0], b[0], S[1], 0, 0, 0);
        S[0] = __builtin_amdgcn_mfma_f32_16x16x32_fp8_fp8(afr[0][t][1], b[1], S[0], 0, 0, 0);
        S[1] = __builtin_amdgcn_mfma_f32_16x16x32_fp8_fp8(afr[1][t][1], b[1], S[1], 0, 0, 0);
      }
      #pragma unroll
      for (int mi = 0; mi < 2; ++mi)
        #pragma unroll
        for (int r = 0; r < 4; ++r)
          accd[dir][mi][r] += __builtin_amdgcn_exp2f(S[mi][r] * csc);

      __syncthreads();   // readers done with rbuf; prefetch drained for next iter
    }
    // loop ends with __syncthreads -> safe to re-preload buffer 0 for next dir
  }

  // Epilogue: combine dirs in-register, LDS transpose, coalesced f32 out stores.
  // C/D layout: col = lane&15, row = (lane>>4)*4 + reg.
  float* ebuf = (float*)smem;                         // [64][36] f32 = 9216 B
  #pragma unroll
  for (int mi = 0; mi < 2; ++mi){
    const int n = wn + lm;
    #pragma unroll
    for (int r = 0; r < 4; ++r){
      const int m = wm + mi * 16 + (kh << 2) + r;
      const float p0 = accd[0][mi][r], p1 = accd[1][mi][r];
      ebuf[m * 36 + n] = -(__logf(1.f + p0) + __logf(1.f + p1));
    }
  }
  __syncthreads();
  #pragma unroll
  for (int p = 0; p < 2; ++p){
    const int i   = tid + p * 256;     // 0..511 (float4 units of the 64x32 tile)
    const int row = i >> 3;
    const int c4  = i & 7;
    *(f32x4*)(&out[(size_t)(r0 + row) * 256 + s0 + c4 * 4]) = *(const f32x4*)(&ebuf[row * 36 + c4 * 4]);
  }
}

extern "C" void kernel_launch(void* const* d_in, const int* in_sizes, int n_in,
                              void* d_out, int out_size, void* d_ws, size_t ws_size,
                              hipStream_t stream){
  const float* V = (const float*)d_in[2];   // back_VF  (pre_VF/pre_AF unused by reference)
  const float* A = (const float*)d_in[3];   // back_AF
  float* out = (float*)d_out;
  float* ivn = (float*)((char*)d_ws + IVN_OFF);
  float* icn = (float*)((char*)d_ws + ICN_OFF);
  float* csq = (float*)((char*)d_ws + CSQ_OFF);
  unsigned char* mats = (unsigned char*)((char*)d_ws + MATS_OFF);

  cast_ns_k<<<dim3(8, 32, 2), 256, 0, stream>>>(V, A, mats, csq);
  nreduce_k<<<dim3(32, 2), 256, 0, stream>>>(csq, ivn, icn);
  gemm_both_k<<<dim3(8, 128), 256, 0, stream>>>(mats, ivn, icn, out);
}

// Round 9
// 132.901 us; speedup vs baseline: 1.0069x; 1.0069x over previous
//
#include <hip/hip_runtime.h>
#include <cstdint>

// Problem constants: B=32, T=D=256, rows R = B*T = 8192, K = 256.
#define R_TOT 8192
#define KD    256
#define SLOT  ((size_t)R_TOT * KD)            // bytes per fp8 image (2,097,152)
// ws layout (bytes):  total ~4.8 MB
#define IVN_OFF  0                            // 64 f32: 1/frobenius-norm [ten][j]
#define ICN_OFF  256                          // 2*8192 f32: 1/col-norm [ten][j][s]
#define CSQ_OFF  (ICN_OFF + 65536)            // 8 tc-partials x 2*8192 f32 = 512 KB
#define MATS_OFF (CSQ_OFF + 524288)           // 2 fp8 images (Vq, Aq), permuted+swizzled, 4 MB

typedef float f32x4 __attribute__((ext_vector_type(4)));
typedef long  lx2   __attribute__((ext_vector_type(2)));   // 16B = 2 fp8 MFMA operands

__device__ __forceinline__ void glds16(const void* g, void* l){
  __builtin_amdgcn_global_load_lds((const __attribute__((address_space(1))) uint32_t*)g,
                                   (__attribute__((address_space(3))) uint32_t*)l, 16, 0, 0);
}

// Image byte layout per 256-B row r (k = 0..255):
//   t = k>>6, half = (k>>5)&1, kh = (k>>3)&3, lo = k&7
//   chunk q = t*4 + kh, stored at 16B slot (q ^ (r&15)), byte half*8 + lo.
// => one ds_read_b128 at slot ((t*4+kh) ^ (r&15)) yields fp8 MFMA fragments for
//    k-chunks 2t and 2t+1 at quad kh; XOR swizzle -> conflict-free (verified R7/R8).
__global__ void cast_ns_k(const float* __restrict__ V, const float* __restrict__ A,
                          unsigned char* __restrict__ mats, float* __restrict__ csq){
  const int tc = blockIdx.x, j = blockIdx.y, ten = blockIdx.z;
  const int tid = threadIdx.x;
  const int g    = tid & 31;                 // d-chunk of 8 floats
  const int tsub = tid >> 5;                 // 0..7
  const int q    = ((g >> 3) << 2) | (g & 3);
  const int half = (g >> 2) & 1;
  const float* X = (ten ? A : V) + (size_t)j * 65536;
  unsigned char* M = mats + (size_t)ten * SLOT + (size_t)j * 65536;
  float cs[8];
  #pragma unroll
  for (int e = 0; e < 8; ++e) cs[e] = 0.f;
  #pragma unroll
  for (int tt = 0; tt < 4; ++tt){
    const int t = tc * 32 + tt * 8 + tsub;
    const float4 p0 = *(const float4*)(X + t * 256 + g * 8);
    const float4 p1 = *(const float4*)(X + t * 256 + g * 8 + 4);
    cs[0] += p0.x * p0.x; cs[1] += p0.y * p0.y; cs[2] += p0.z * p0.z; cs[3] += p0.w * p0.w;
    cs[4] += p1.x * p1.x; cs[5] += p1.y * p1.y; cs[6] += p1.z * p1.z; cs[7] += p1.w * p1.w;
    int d0 = __builtin_amdgcn_cvt_pk_fp8_f32(p0.x, p0.y, 0, false);
    d0     = __builtin_amdgcn_cvt_pk_fp8_f32(p0.z, p0.w, d0, true);
    int d1 = __builtin_amdgcn_cvt_pk_fp8_f32(p1.x, p1.y, 0, false);
    d1     = __builtin_amdgcn_cvt_pk_fp8_f32(p1.z, p1.w, d1, true);
    int2 o; o.x = d0; o.y = d1;
    *(int2*)(M + (size_t)t * 256 + (((q ^ (t & 15)) << 4) | (half << 3))) = o;
  }
  __shared__ float red[8][256];
  #pragma unroll
  for (int e = 0; e < 8; ++e) red[tsub][g * 8 + e] = cs[e];
  __syncthreads();
  float s = 0.f;
  #pragma unroll
  for (int gg = 0; gg < 8; ++gg) s += red[gg][tid];
  csq[(size_t)((tc * 2 + ten) * 32 + j) * 256 + tid] = s;
}

// Finish norms: sum 8 tc-partials; icn = rsqrt, ivn = rsqrt of row-sum. Grid (32, 2).
__global__ void nreduce_k(const float* __restrict__ csq, float* __restrict__ ivn,
                          float* __restrict__ icn){
  const int j = blockIdx.x, ten = blockIdx.y, s = threadIdx.x;
  float c = 0.f;
  #pragma unroll
  for (int tc = 0; tc < 8; ++tc)
    c += csq[(size_t)((tc * 2 + ten) * 32 + j) * 256 + s];
  icn[ten * 8192 + j * 256 + s] = rsqrtf(c + 1e-18f);
  __shared__ float red[256];
  red[s] = c; __syncthreads();
  for (int off = 128; off > 0; off >>= 1){
    if (s < off) red[s] += red[s + off];
    __syncthreads();
  }
  if (s == 0) ivn[ten * 32 + j] = rsqrtf(red[0] + 1e-18f);
}

// v9: both dirs in the SAME j-iteration. Block tile 64 rows x 32 cols, 4 waves of
// 32x16 (each wave computes its (m,n) range for BOTH dirs). Per j: stage A-col tile
// AND V-col tile (16 KB) -> 32 KB dbuf LDS, 4 blocks/CU. Per wave-iter: 8 ds_read,
// 32 MFMA (R7's 4:1 ratio), 31 barriers total. Fused log1p-combine epilogue.
__global__ __launch_bounds__(256, 4) void gemm_both_k(const unsigned char* __restrict__ mats,
                                                      const float* __restrict__ ivn,
                                                      const float* __restrict__ icn,
                                                      float* __restrict__ out){
  __shared__ __align__(16) char smem[32768];          // 2 phases x (8KB A-cols + 8KB V-cols)
  const int tid  = threadIdx.x;
  const int lane = tid & 63;
  const int w    = tid >> 6;
  const int wm   = (w & 1) * 32;        // wave row offset in 64-row block tile
  const int wn   = (w >> 1) * 16;       // wave col offset in 32-col block tile
  const int wno  = wn << 8;             // byte offset of col group in an 8KB LDS tile
  const int lm   = lane & 15;
  const int kh   = lane >> 4;           // 0..3
  const int s0   = blockIdx.x * 32;
  const int rb   = blockIdx.y;
  const int r0   = rb * 64;
  const int ib   = rb >> 2;             // batch index of this row tile (excluded diagonal)

  const unsigned char* Vq = mats;                 // dir0 rows / dir1 cols
  const unsigned char* Aq = mats + SLOT;          // dir1 rows / dir0 cols
  const float l2e = 1.44269504088896340736f;
  const float sivn0 = ivn[ib] * l2e;              // dir0 row scale (1/|V_i|F) * log2e
  const float sivn1 = ivn[32 + ib] * l2e;         // dir1 row scale (1/|A_i|F) * log2e
  const float* icn0 = icn + 8192 + s0 + wn + lm;  // dir0 col scales (colnorm of A)
  const float* icn1 = icn +        s0 + wn + lm;  // dir1 col scales (colnorm of V)

  // A-fragments for both dirs: m = r0 + wm + mi*16 + lm; slot (t*4+kh) ^ lm.
  lx2 afr[2][2][4];                     // [dir][mi][t], 64 VGPRs
  #pragma unroll
  for (int d = 0; d < 2; ++d)
    #pragma unroll
    for (int mi = 0; mi < 2; ++mi){
      const unsigned char* rp = (d ? Aq : Vq) + (size_t)(r0 + wm + mi * 16 + lm) * 256;
      #pragma unroll
      for (int t = 0; t < 4; ++t)
        afr[d][mi][t] = *(const lx2*)(rp + (((((t << 2) | kh)) ^ lm) << 4));
    }
  #pragma unroll
  for (int d = 0; d < 2; ++d)
    #pragma unroll
    for (int mi = 0; mi < 2; ++mi)
      #pragma unroll
      for (int t = 0; t < 4; ++t)
        asm volatile("" : "+v"(afr[d][mi][t]));

  // ds_read addrs (j/dir-invariant): addr(t) = lm*256 + (((t*4+kh) ^ lm)<<4) (+wno, +half).
  int a4[4];
  {
    const int base  = lm * 256 + ((kh ^ (lm & 3)) << 4);   // bits 6-7 clear
    const int base2 = base ^ ((lm >> 2) << 6);
    #pragma unroll
    for (int t = 0; t < 4; ++t) a4[t] = base2 ^ (t << 6);
  }

  f32x4 accd[2][2];                     // [dir][mi]
  #pragma unroll
  for (int d = 0; d < 2; ++d)
    #pragma unroll
    for (int mi = 0; mi < 2; ++mi)
      accd[d][mi] = f32x4{0.f, 0.f, 0.f, 0.f};

  // Preload j(0): A-cols into half 0, V-cols into half 1 (4 chunks/thread).
  {
    const int j0 = (ib == 0) ? 1 : 0;
    const unsigned char* sA = Aq + ((size_t)j0 * 256 + s0) * 256;
    const unsigned char* sV = Vq + ((size_t)j0 * 256 + s0) * 256;
    #pragma unroll
    for (int c = 0; c < 2; ++c)
      glds16(sA + (size_t)(c * 256 + tid) * 16, smem + (c * 256 + w * 64) * 16);
    #pragma unroll
    for (int c = 0; c < 2; ++c)
      glds16(sV + (size_t)(c * 256 + tid) * 16, smem + 8192 + (c * 256 + w * 64) * 16);
  }
  __syncthreads();

  for (int jj = 0; jj < 31; ++jj){
    const int j = jj + (jj >= ib ? 1 : 0);
    if (jj < 30){
      const int jn = (jj + 1) + ((jj + 1) >= ib ? 1 : 0);
      const unsigned char* sA = Aq + ((size_t)jn * 256 + s0) * 256;
      const unsigned char* sV = Vq + ((size_t)jn * 256 + s0) * 256;
      char* dst = smem + (((jj + 1) & 1) << 14);
      #pragma unroll
      for (int c = 0; c < 2; ++c)
        glds16(sA + (size_t)(c * 256 + tid) * 16, dst + (c * 256 + w * 64) * 16);
      #pragma unroll
      for (int c = 0; c < 2; ++c)
        glds16(sV + (size_t)(c * 256 + tid) * 16, dst + 8192 + (c * 256 + w * 64) * 16);
    }

    const float csc0 = sivn0 * icn0[j * 256];   // dir0 column scale for block j
    const float csc1 = sivn1 * icn1[j * 256];   // dir1 column scale for block j

    const char* rbuf = smem + ((jj & 1) << 14);
    f32x4 S[2][2];
    #pragma unroll
    for (int d = 0; d < 2; ++d)
      #pragma unroll
      for (int mi = 0; mi < 2; ++mi)
        S[d][mi] = f32x4{0.f, 0.f, 0.f, 0.f};

    #pragma unroll
    for (int t = 0; t < 4; ++t){
      lx2 ba = *(const lx2*)(rbuf + wno + a4[t]);          // dir0 cols (from Aq)
      lx2 bv = *(const lx2*)(rbuf + 8192 + wno + a4[t]);   // dir1 cols (from Vq)
      S[0][0] = __builtin_amdgcn_mfma_f32_16x16x32_fp8_fp8(afr[0][0][t][0], ba[0], S[0][0], 0, 0, 0);
      S[0][1] = __builtin_amdgcn_mfma_f32_16x16x32_fp8_fp8(afr[0][1][t][0], ba[0], S[0][1], 0, 0, 0);
      S[1][0] = __builtin_amdgcn_mfma_f32_16x16x32_fp8_fp8(afr[1][0][t][0], bv[0], S[1][0], 0, 0, 0);
      S[1][1] = __builtin_amdgcn_mfma_f32_16x16x32_fp8_fp8(afr[1][1][t][0], bv[0], S[1][1], 0, 0, 0);
      S[0][0] = __builtin_amdgcn_mfma_f32_16x16x32_fp8_fp8(afr[0][0][t][1], ba[1], S[0][0], 0, 0, 0);
      S[0][1] = __builtin_amdgcn_mfma_f32_16x16x32_fp8_fp8(afr[0][1][t][1], ba[1], S[0][1], 0, 0, 0);
      S[1][0] = __builtin_amdgcn_mfma_f32_16x16x32_fp8_fp8(afr[1][0][t][1], bv[1], S[1][0], 0, 0, 0);
      S[1][1] = __builtin_amdgcn_mfma_f32_16x16x32_fp8_fp8(afr[1][1][t][1], bv[1], S[1][1], 0, 0, 0);
    }
    #pragma unroll
    for (int mi = 0; mi < 2; ++mi)
      #pragma unroll
      for (int r = 0; r < 4; ++r){
        accd[0][mi][r] += __builtin_amdgcn_exp2f(S[0][mi][r] * csc0);
        accd[1][mi][r] += __builtin_amdgcn_exp2f(S[1][mi][r] * csc1);
      }

    __syncthreads();   // readers done with rbuf; prefetch drained for next iter
  }

  // Epilogue: combine dirs in-register, LDS transpose, coalesced f32 out stores.
  // C/D layout: col = lane&15, row = (lane>>4)*4 + reg.
  float* ebuf = (float*)smem;                         // [64][36] f32 = 9216 B
  #pragma unroll
  for (int mi = 0; mi < 2; ++mi){
    const int n = wn + lm;
    #pragma unroll
    for (int r = 0; r < 4; ++r){
      const int m = wm + mi * 16 + (kh << 2) + r;
      const float p0 = accd[0][mi][r], p1 = accd[1][mi][r];
      ebuf[m * 36 + n] = -(__logf(1.f + p0) + __logf(1.f + p1));
    }
  }
  __syncthreads();
  #pragma unroll
  for (int p = 0; p < 2; ++p){
    const int i   = tid + p * 256;     // 0..511 (float4 units of the 64x32 tile)
    const int row = i >> 3;
    const int c4  = i & 7;
    *(f32x4*)(&out[(size_t)(r0 + row) * 256 + s0 + c4 * 4]) = *(const f32x4*)(&ebuf[row * 36 + c4 * 4]);
  }
}

extern "C" void kernel_launch(void* const* d_in, const int* in_sizes, int n_in,
                              void* d_out, int out_size, void* d_ws, size_t ws_size,
                              hipStream_t stream){
  const float* V = (const float*)d_in[2];   // back_VF  (pre_VF/pre_AF unused by reference)
  const float* A = (const float*)d_in[3];   // back_AF
  float* out = (float*)d_out;
  float* ivn = (float*)((char*)d_ws + IVN_OFF);
  float* icn = (float*)((char*)d_ws + ICN_OFF);
  float* csq = (float*)((char*)d_ws + CSQ_OFF);
  unsigned char* mats = (unsigned char*)((char*)d_ws + MATS_OFF);

  cast_ns_k<<<dim3(8, 32, 2), 256, 0, stream>>>(V, A, mats, csq);
  nreduce_k<<<dim3(32, 2), 256, 0, stream>>>(csq, ivn, icn);
  gemm_both_k<<<dim3(8, 128), 256, 0, stream>>>(mats, ivn, icn, out);
}

// Round 10
// 128.959 us; speedup vs baseline: 1.0377x; 1.0306x over previous
//
#include <hip/hip_runtime.h>
#include <cstdint>

// Problem constants: B=32, T=D=256, rows R = B*T = 8192, K = 256.
#define R_TOT 8192
#define KD    256
#define SLOT  ((size_t)R_TOT * KD)            // bytes per fp8 image (2,097,152)
// ws layout (bytes):  total ~4.8 MB
#define IVN_OFF  0                            // 64 f32: 1/frobenius-norm [ten][j]
#define ICN_OFF  256                          // 2*8192 f32: 1/col-norm [ten][j][s]
#define CSQ_OFF  (ICN_OFF + 65536)            // 8 tc-partials x 2*8192 f32 = 512 KB
#define MATS_OFF (CSQ_OFF + 524288)           // 2 fp8 images (Vq, Aq), permuted+swizzled, 4 MB

typedef float f32x4 __attribute__((ext_vector_type(4)));
typedef long  lx2   __attribute__((ext_vector_type(2)));   // 16B = 2 fp8 MFMA operands

__device__ __forceinline__ void glds16(const void* g, void* l){
  __builtin_amdgcn_global_load_lds((const __attribute__((address_space(1))) uint32_t*)g,
                                   (__attribute__((address_space(3))) uint32_t*)l, 16, 0, 0);
}

// Image byte layout per 256-B row r (k = 0..255):
//   t = k>>6, half = (k>>5)&1, kh = (k>>3)&3, lo = k&7
//   chunk q = t*4 + kh, stored at 16B slot (q ^ (r&15)), byte half*8 + lo.
// => one ds_read_b128 at slot ((t*4+kh) ^ (r&15)) yields fp8 MFMA fragments for
//    k-chunks 2t and 2t+1 at quad kh; XOR swizzle -> conflict-free (verified R7-R9).
__global__ void cast_ns_k(const float* __restrict__ V, const float* __restrict__ A,
                          unsigned char* __restrict__ mats, float* __restrict__ csq){
  const int tc = blockIdx.x, j = blockIdx.y, ten = blockIdx.z;
  const int tid = threadIdx.x;
  const int g    = tid & 31;                 // d-chunk of 8 floats
  const int tsub = tid >> 5;                 // 0..7
  const int q    = ((g >> 3) << 2) | (g & 3);
  const int half = (g >> 2) & 1;
  const float* X = (ten ? A : V) + (size_t)j * 65536;
  unsigned char* M = mats + (size_t)ten * SLOT + (size_t)j * 65536;
  float cs[8];
  #pragma unroll
  for (int e = 0; e < 8; ++e) cs[e] = 0.f;
  #pragma unroll
  for (int tt = 0; tt < 4; ++tt){
    const int t = tc * 32 + tt * 8 + tsub;
    const float4 p0 = *(const float4*)(X + t * 256 + g * 8);
    const float4 p1 = *(const float4*)(X + t * 256 + g * 8 + 4);
    cs[0] += p0.x * p0.x; cs[1] += p0.y * p0.y; cs[2] += p0.z * p0.z; cs[3] += p0.w * p0.w;
    cs[4] += p1.x * p1.x; cs[5] += p1.y * p1.y; cs[6] += p1.z * p1.z; cs[7] += p1.w * p1.w;
    int d0 = __builtin_amdgcn_cvt_pk_fp8_f32(p0.x, p0.y, 0, false);
    d0     = __builtin_amdgcn_cvt_pk_fp8_f32(p0.z, p0.w, d0, true);
    int d1 = __builtin_amdgcn_cvt_pk_fp8_f32(p1.x, p1.y, 0, false);
    d1     = __builtin_amdgcn_cvt_pk_fp8_f32(p1.z, p1.w, d1, true);
    int2 o; o.x = d0; o.y = d1;
    *(int2*)(M + (size_t)t * 256 + (((q ^ (t & 15)) << 4) | (half << 3))) = o;
  }
  __shared__ float red[8][256];
  #pragma unroll
  for (int e = 0; e < 8; ++e) red[tsub][g * 8 + e] = cs[e];
  __syncthreads();
  float s = 0.f;
  #pragma unroll
  for (int gg = 0; gg < 8; ++gg) s += red[gg][tid];
  csq[(size_t)((tc * 2 + ten) * 32 + j) * 256 + tid] = s;
}

// Finish norms: sum 8 tc-partials; icn = rsqrt, ivn = rsqrt of row-sum. Grid (32, 2).
__global__ void nreduce_k(const float* __restrict__ csq, float* __restrict__ ivn,
                          float* __restrict__ icn){
  const int j = blockIdx.x, ten = blockIdx.y, s = threadIdx.x;
  float c = 0.f;
  #pragma unroll
  for (int tc = 0; tc < 8; ++tc)
    c += csq[(size_t)((tc * 2 + ten) * 32 + j) * 256 + s];
  icn[ten * 8192 + j * 256 + s] = rsqrtf(c + 1e-18f);
  __shared__ float red[256];
  red[s] = c; __syncthreads();
  for (int off = 128; off > 0; off >>= 1){
    if (s < off) red[s] += red[s + off];
    __syncthreads();
  }
  if (s == 0) ivn[ten * 32 + j] = rsqrtf(red[0] + 1e-18f);
}

// v10: BARRIER-FREE K-loop via wave-private double-buffered LDS.
// Block tile 64 rows x 32 cols x 2 dirs; wave w owns (dir = w>>1, 16-col slice).
// Each wave stages ITS OWN 4KB B-slice per j with global_load_lds into a private
// 8KB dbuf region (32KB total, 4 blocks/CU); consumer == producer wave, so the
// only sync is the compiler's vmcnt before ds_read — NO __syncthreads in the loop.
// afr[4][4] = 64 VGPRs (all 64 rows of the wave's dir). Fused log1p epilogue.
__global__ __launch_bounds__(256, 4) void gemm_both_k(const unsigned char* __restrict__ mats,
                                                      const float* __restrict__ ivn,
                                                      const float* __restrict__ icn,
                                                      float* __restrict__ out){
  __shared__ __align__(16) char smem[32768];          // 4 waves x (2 x 4KB); epilogue reuse
  const int tid  = threadIdx.x;
  const int lane = tid & 63;
  const int w    = tid >> 6;
  const int dir  = w >> 1;              // waves 0,1 -> dir0; 2,3 -> dir1
  const int wn   = (w & 1) * 16;        // wave col slice in 32-col block tile
  const int lm   = lane & 15;
  const int kh   = lane >> 4;           // 0..3
  const int s0   = blockIdx.x * 32;
  const int rb   = blockIdx.y;
  const int r0   = rb * 64;
  const int ib   = rb >> 2;             // batch index of this row tile (excluded diagonal)

  // dir0: rows Vq (scale 1/|V_i|F), cols Aq (scale 1/colnorm A); dir1 swapped.
  const unsigned char* rowmat = mats + (size_t)dir * SLOT;
  const unsigned char* colmat = mats + (size_t)(1 - dir) * SLOT;
  const float sivn = ivn[dir * 32 + ib] * 1.44269504088896340736f;  // * log2(e)
  const float* icnb = icn + (size_t)(1 - dir) * 8192 + s0 + wn + lm;

  // A-fragments: ALL 64 rows of this wave's dir. m = r0 + mi*16 + lm; slot (t*4+kh)^lm.
  lx2 afr[4][4];                        // 64 VGPRs
  #pragma unroll
  for (int mi = 0; mi < 4; ++mi){
    const unsigned char* rp = rowmat + (size_t)(r0 + mi * 16 + lm) * 256;
    #pragma unroll
    for (int t = 0; t < 4; ++t)
      afr[mi][t] = *(const lx2*)(rp + (((((t << 2) | kh)) ^ lm) << 4));
  }
  #pragma unroll
  for (int mi = 0; mi < 4; ++mi)
    #pragma unroll
    for (int t = 0; t < 4; ++t)
      asm volatile("" : "+v"(afr[mi][t]));

  // Wave-private LDS region and j-invariant ds_read offsets.
  // Region row = col-within-slice (global row index (s0+wn+lm) & 15 == lm).
  char* wbase = smem + w * 8192;
  int a4[4];
  {
    const int base  = lm * 256 + ((kh ^ (lm & 3)) << 4);   // bits 6-7 clear
    const int base2 = base ^ ((lm >> 2) << 6);
    #pragma unroll
    for (int t = 0; t < 4; ++t) a4[t] = base2 ^ (t << 6);
  }
  const int lo16 = lane * 16;           // lane offset within a 1KB chunk-group

  f32x4 acc[4];
  #pragma unroll
  for (int mi = 0; mi < 4; ++mi)
    acc[mi] = f32x4{0.f, 0.f, 0.f, 0.f};

  // Preload j(0) into phase 0 (4KB = 4 chunk-groups, 1 glds16 per lane each).
  {
    const int j0 = (ib == 0) ? 1 : 0;
    const unsigned char* src = colmat + ((size_t)j0 * 256 + s0 + wn) * 256;
    #pragma unroll
    for (int c = 0; c < 4; ++c)
      glds16(src + c * 1024 + lo16, wbase + c * 1024 + lo16);
  }

  for (int jj = 0; jj < 31; ++jj){
    const int j = jj + (jj >= ib ? 1 : 0);
    if (jj < 30){                       // prefetch j(jj+1) into the other phase
      const int jn = (jj + 1) + ((jj + 1) >= ib ? 1 : 0);
      const unsigned char* src = colmat + ((size_t)jn * 256 + s0 + wn) * 256;
      char* dst = wbase + (((jj + 1) & 1) << 12);
      #pragma unroll
      for (int c = 0; c < 4; ++c)
        glds16(src + c * 1024 + lo16, dst + c * 1024 + lo16);
    }

    const float csc = sivn * icnb[j * 256];   // this lane's column scale for block j

    const char* rbuf = wbase + ((jj & 1) << 12);
    f32x4 S[4];
    #pragma unroll
    for (int mi = 0; mi < 4; ++mi)
      S[mi] = f32x4{0.f, 0.f, 0.f, 0.f};

    #pragma unroll
    for (int t = 0; t < 4; ++t){
      lx2 b = *(const lx2*)(rbuf + a4[t]);   // vmcnt-guarded by compiler, wave-local
      S[0] = __builtin_amdgcn_mfma_f32_16x16x32_fp8_fp8(afr[0][t][0], b[0], S[0], 0, 0, 0);
      S[1] = __builtin_amdgcn_mfma_f32_16x16x32_fp8_fp8(afr[1][t][0], b[0], S[1], 0, 0, 0);
      S[2] = __builtin_amdgcn_mfma_f32_16x16x32_fp8_fp8(afr[2][t][0], b[0], S[2], 0, 0, 0);
      S[3] = __builtin_amdgcn_mfma_f32_16x16x32_fp8_fp8(afr[3][t][0], b[0], S[3], 0, 0, 0);
      S[0] = __builtin_amdgcn_mfma_f32_16x16x32_fp8_fp8(afr[0][t][1], b[1], S[0], 0, 0, 0);
      S[1] = __builtin_amdgcn_mfma_f32_16x16x32_fp8_fp8(afr[1][t][1], b[1], S[1], 0, 0, 0);
      S[2] = __builtin_amdgcn_mfma_f32_16x16x32_fp8_fp8(afr[2][t][1], b[1], S[2], 0, 0, 0);
      S[3] = __builtin_amdgcn_mfma_f32_16x16x32_fp8_fp8(afr[3][t][1], b[1], S[3], 0, 0, 0);
    }
    #pragma unroll
    for (int mi = 0; mi < 4; ++mi)
      #pragma unroll
      for (int r = 0; r < 4; ++r)
        acc[mi][r] += __builtin_amdgcn_exp2f(S[mi][r] * csc);
    // NO __syncthreads: next iter's ds_reads are guarded by this wave's own vmcnt.
  }

  // Epilogue: per-dir log1p into LDS ([2][64][36] f32 = 18KB), combine, coalesced store.
  // C/D layout: col = lane&15, row = (lane>>4)*4 + reg.
  __syncthreads();                      // all waves' loop reads + glds drained
  float* ebuf = (float*)smem;
  #pragma unroll
  for (int mi = 0; mi < 4; ++mi){
    const int n = wn + lm;
    #pragma unroll
    for (int r = 0; r < 4; ++r){
      const int m = mi * 16 + (kh << 2) + r;
      ebuf[(dir * 64 + m) * 36 + n] = __logf(1.f + acc[mi][r]);
    }
  }
  __syncthreads();
  #pragma unroll
  for (int p = 0; p < 2; ++p){
    const int i   = tid + p * 256;     // 0..511 (float4 units of the 64x32 tile)
    const int row = i >> 3;
    const int c4  = i & 7;
    const f32x4 e0 = *(const f32x4*)(&ebuf[row * 36 + c4 * 4]);
    const f32x4 e1 = *(const f32x4*)(&ebuf[(64 + row) * 36 + c4 * 4]);
    f32x4 o;
    #pragma unroll
    for (int e = 0; e < 4; ++e) o[e] = -(e0[e] + e1[e]);
    *(f32x4*)(&out[(size_t)(r0 + row) * 256 + s0 + c4 * 4]) = o;
  }
}

extern "C" void kernel_launch(void* const* d_in, const int* in_sizes, int n_in,
                              void* d_out, int out_size, void* d_ws, size_t ws_size,
                              hipStream_t stream){
  const float* V = (const float*)d_in[2];   // back_VF  (pre_VF/pre_AF unused by reference)
  const float* A = (const float*)d_in[3];   // back_AF
  float* out = (float*)d_out;
  float* ivn = (float*)((char*)d_ws + IVN_OFF);
  float* icn = (float*)((char*)d_ws + ICN_OFF);
  float* csq = (float*)((char*)d_ws + CSQ_OFF);
  unsigned char* mats = (unsigned char*)((char*)d_ws + MATS_OFF);

  cast_ns_k<<<dim3(8, 32, 2), 256, 0, stream>>>(V, A, mats, csq);
  nreduce_k<<<dim3(32, 2), 256, 0, stream>>>(csq, ivn, icn);
  gemm_both_k<<<dim3(8, 128), 256, 0, stream>>>(mats, ivn, icn, out);
}

// Round 11
// 121.984 us; speedup vs baseline: 1.0970x; 1.0572x over previous
//
#include <hip/hip_runtime.h>
#include <cstdint>

// Problem constants: B=32, T=D=256, rows R = B*T = 8192, K = 256.
#define R_TOT 8192
#define KD    256
#define SLOT  ((size_t)R_TOT * KD)            // bytes per fp8 image (2,097,152)
// ws layout (bytes):  total ~4.8 MB
#define IVN_OFF  0                            // 64 f32: 1/frobenius-norm [ten][j]
#define ICN_OFF  256                          // 2*8192 f32: 1/col-norm [ten][j][s]
#define CSQ_OFF  (ICN_OFF + 65536)            // 8 tc-partials x 2*8192 f32 = 512 KB
#define MATS_OFF (CSQ_OFF + 524288)           // 2 fp8 images (Vq, Aq), swizzled, 4 MB

typedef float f32x4 __attribute__((ext_vector_type(4)));
typedef int   i32x4 __attribute__((ext_vector_type(4)));
typedef int   i32x8 __attribute__((ext_vector_type(8)));   // 32 fp8 = one MX MFMA operand

__device__ __forceinline__ void glds16(const void* g, void* l){
  __builtin_amdgcn_global_load_lds((const __attribute__((address_space(1))) uint32_t*)g,
                                   (__attribute__((address_space(3))) uint32_t*)l, 16, 0, 0);
}

// v11 image layout: plain k-order rows (256 B per image row r), 16B chunk c
// (k in [c*16, c*16+16)) stored at 16B slot c ^ (r & 15). XOR swizzle keeps
// MFMA-layout ds_read_b128 conflict-free (same family verified R7-R10).
__global__ void cast_ns_k(const float* __restrict__ V, const float* __restrict__ A,
                          unsigned char* __restrict__ mats, float* __restrict__ csq){
  const int tc = blockIdx.x, j = blockIdx.y, ten = blockIdx.z;
  const int tid = threadIdx.x;
  const int g    = tid & 31;                 // d-chunk of 8 floats = 8 fp8 bytes
  const int tsub = tid >> 5;                 // 0..7
  const int c    = g >> 1;                   // 16B chunk index 0..15
  const int half = g & 1;                    // which 8B half of the chunk
  const float* X = (ten ? A : V) + (size_t)j * 65536;
  unsigned char* M = mats + (size_t)ten * SLOT + (size_t)j * 65536;
  float cs[8];
  #pragma unroll
  for (int e = 0; e < 8; ++e) cs[e] = 0.f;
  #pragma unroll
  for (int tt = 0; tt < 4; ++tt){
    const int t = tc * 32 + tt * 8 + tsub;
    const float4 p0 = *(const float4*)(X + t * 256 + g * 8);
    const float4 p1 = *(const float4*)(X + t * 256 + g * 8 + 4);
    cs[0] += p0.x * p0.x; cs[1] += p0.y * p0.y; cs[2] += p0.z * p0.z; cs[3] += p0.w * p0.w;
    cs[4] += p1.x * p1.x; cs[5] += p1.y * p1.y; cs[6] += p1.z * p1.z; cs[7] += p1.w * p1.w;
    int d0 = __builtin_amdgcn_cvt_pk_fp8_f32(p0.x, p0.y, 0, false);
    d0     = __builtin_amdgcn_cvt_pk_fp8_f32(p0.z, p0.w, d0, true);
    int d1 = __builtin_amdgcn_cvt_pk_fp8_f32(p1.x, p1.y, 0, false);
    d1     = __builtin_amdgcn_cvt_pk_fp8_f32(p1.z, p1.w, d1, true);
    int2 o; o.x = d0; o.y = d1;
    *(int2*)(M + (size_t)t * 256 + (((c ^ (t & 15)) << 4) | (half << 3))) = o;
  }
  __shared__ float red[8][256];
  #pragma unroll
  for (int e = 0; e < 8; ++e) red[tsub][g * 8 + e] = cs[e];
  __syncthreads();
  float s = 0.f;
  #pragma unroll
  for (int gg = 0; gg < 8; ++gg) s += red[gg][tid];
  csq[(size_t)((tc * 2 + ten) * 32 + j) * 256 + tid] = s;
}

// Finish norms: sum 8 tc-partials; icn = rsqrt, ivn = rsqrt of row-sum. Grid (32, 2).
__global__ void nreduce_k(const float* __restrict__ csq, float* __restrict__ ivn,
                          float* __restrict__ icn){
  const int j = blockIdx.x, ten = blockIdx.y, s = threadIdx.x;
  float c = 0.f;
  #pragma unroll
  for (int tc = 0; tc < 8; ++tc)
    c += csq[(size_t)((tc * 2 + ten) * 32 + j) * 256 + s];
  icn[ten * 8192 + j * 256 + s] = rsqrtf(c + 1e-18f);
  __shared__ float red[256];
  red[s] = c; __syncthreads();
  for (int off = 128; off > 0; off >>= 1){
    if (s < off) red[s] += red[s + off];
    __syncthreads();
  }
  if (s == 0) ivn[ten * 32 + j] = rsqrtf(red[0] + 1e-18f);
}

// v11: MX-fp8 K=128 MFMA (unit scales) in R10's barrier-free wave-private structure.
// mfma_scale_f32_16x16x128_f8f6f4: lane holds 32 contiguous k-bytes (quad kh ->
// k in [kh*32, kh*32+32)); 8 MFMAs per j-iter (4 mi x 2 K-halves) vs 32 before.
// Wave w owns (dir = w>>1, 16-col slice); stages its own 4KB B-slice per j into a
// private 8KB dbuf LDS region; NO __syncthreads in the K-loop.
__global__ __launch_bounds__(256, 4) void gemm_both_k(const unsigned char* __restrict__ mats,
                                                      const float* __restrict__ ivn,
                                                      const float* __restrict__ icn,
                                                      float* __restrict__ out){
  __shared__ __align__(16) char smem[32768];          // 4 waves x (2 x 4KB); epilogue reuse
  const int tid  = threadIdx.x;
  const int lane = tid & 63;
  const int w    = tid >> 6;
  const int dir  = w >> 1;              // waves 0,1 -> dir0; 2,3 -> dir1
  const int wn   = (w & 1) * 16;        // wave col slice in 32-col block tile
  const int lm   = lane & 15;
  const int kh   = lane >> 4;           // 0..3 (k-quad: k in [kh*32, kh*32+32) per K-half)
  const int s0   = blockIdx.x * 32;
  const int rb   = blockIdx.y;
  const int r0   = rb * 64;
  const int ib   = rb >> 2;             // batch index of this row tile (excluded diagonal)

  // dir0: rows Vq (scale 1/|V_i|F), cols Aq (scale 1/colnorm A); dir1 swapped.
  const unsigned char* rowmat = mats + (size_t)dir * SLOT;
  const unsigned char* colmat = mats + (size_t)(1 - dir) * SLOT;
  const float sivn = ivn[dir * 32 + ib] * 1.44269504088896340736f;  // * log2(e)
  const float* icnb = icn + (size_t)(1 - dir) * 8192 + s0 + wn + lm;

  // Chunk slots for this lane: K-half t, 16B unit u: slot = (t*8 + kh*2 + u) ^ lm.
  // A-fragments: all 64 rows of this wave's dir; row r&15 == lm. 64 VGPRs.
  i32x8 afr[4][2];                      // [mi][K-half]
  #pragma unroll
  for (int mi = 0; mi < 4; ++mi){
    const unsigned char* rp = rowmat + (size_t)(r0 + mi * 16 + lm) * 256;
    #pragma unroll
    for (int t = 0; t < 2; ++t){
      i32x4 lo = *(const i32x4*)(rp + ((((t << 3) | (kh << 1) | 0) ^ lm) << 4));
      i32x4 hi = *(const i32x4*)(rp + ((((t << 3) | (kh << 1) | 1) ^ lm) << 4));
      afr[mi][t] = i32x8{lo.x, lo.y, lo.z, lo.w, hi.x, hi.y, hi.z, hi.w};
    }
  }
  #pragma unroll
  for (int mi = 0; mi < 4; ++mi)
    #pragma unroll
    for (int t = 0; t < 2; ++t)
      asm volatile("" : "+v"(afr[mi][t]));

  // Wave-private LDS region; j-invariant ds_read offsets (row-in-slice == lm).
  char* wbase = smem + w * 8192;
  int ad[2][2];                         // [K-half][16B unit]
  #pragma unroll
  for (int t = 0; t < 2; ++t)
    #pragma unroll
    for (int u = 0; u < 2; ++u)
      ad[t][u] = lm * 256 + ((((t << 3) | (kh << 1) | u) ^ lm) << 4);
  const int lo16 = lane * 16;           // lane offset within a 1KB chunk-group

  f32x4 acc[4];
  #pragma unroll
  for (int mi = 0; mi < 4; ++mi)
    acc[mi] = f32x4{0.f, 0.f, 0.f, 0.f};

  // Preload j(0) into phase 0 (4KB = 4 chunk-groups, 1 glds16 per lane each).
  {
    const int j0 = (ib == 0) ? 1 : 0;
    const unsigned char* src = colmat + ((size_t)j0 * 256 + s0 + wn) * 256;
    #pragma unroll
    for (int c = 0; c < 4; ++c)
      glds16(src + c * 1024 + lo16, wbase + c * 1024 + lo16);
  }

  for (int jj = 0; jj < 31; ++jj){
    const int j = jj + (jj >= ib ? 1 : 0);
    if (jj < 30){                       // prefetch j(jj+1) into the other phase
      const int jn = (jj + 1) + ((jj + 1) >= ib ? 1 : 0);
      const unsigned char* src = colmat + ((size_t)jn * 256 + s0 + wn) * 256;
      char* dst = wbase + (((jj + 1) & 1) << 12);
      #pragma unroll
      for (int c = 0; c < 4; ++c)
        glds16(src + c * 1024 + lo16, dst + c * 1024 + lo16);
    }

    const float csc = sivn * icnb[j * 256];   // this lane's column scale for block j

    const char* rbuf = wbase + ((jj & 1) << 12);
    i32x8 b[2];
    #pragma unroll
    for (int t = 0; t < 2; ++t){
      i32x4 lo = *(const i32x4*)(rbuf + ad[t][0]);   // vmcnt-guarded, wave-local
      i32x4 hi = *(const i32x4*)(rbuf + ad[t][1]);
      b[t] = i32x8{lo.x, lo.y, lo.z, lo.w, hi.x, hi.y, hi.z, hi.w};
    }

    f32x4 S[4];
    #pragma unroll
    for (int mi = 0; mi < 4; ++mi)
      S[mi] = f32x4{0.f, 0.f, 0.f, 0.f};
    #pragma unroll
    for (int t = 0; t < 2; ++t){
      S[0] = __builtin_amdgcn_mfma_scale_f32_16x16x128_f8f6f4(afr[0][t], b[t], S[0], 0, 0, 0, 127, 0, 127);
      S[1] = __builtin_amdgcn_mfma_scale_f32_16x16x128_f8f6f4(afr[1][t], b[t], S[1], 0, 0, 0, 127, 0, 127);
      S[2] = __builtin_amdgcn_mfma_scale_f32_16x16x128_f8f6f4(afr[2][t], b[t], S[2], 0, 0, 0, 127, 0, 127);
      S[3] = __builtin_amdgcn_mfma_scale_f32_16x16x128_f8f6f4(afr[3][t], b[t], S[3], 0, 0, 0, 127, 0, 127);
    }
    #pragma unroll
    for (int mi = 0; mi < 4; ++mi)
      #pragma unroll
      for (int r = 0; r < 4; ++r)
        acc[mi][r] += __builtin_amdgcn_exp2f(S[mi][r] * csc);
    // NO __syncthreads: next iter's ds_reads are guarded by this wave's own vmcnt.
  }

  // Epilogue: per-dir log1p into LDS ([2][64][36] f32 = 18KB), combine, coalesced store.
  // C/D layout: col = lane&15, row = (lane>>4)*4 + reg (shape-determined, incl. f8f6f4).
  __syncthreads();                      // all waves' loop reads + glds drained
  float* ebuf = (float*)smem;
  #pragma unroll
  for (int mi = 0; mi < 4; ++mi){
    const int n = wn + lm;
    #pragma unroll
    for (int r = 0; r < 4; ++r){
      const int m = mi * 16 + (kh << 2) + r;
      ebuf[(dir * 64 + m) * 36 + n] = __logf(1.f + acc[mi][r]);
    }
  }
  __syncthreads();
  #pragma unroll
  for (int p = 0; p < 2; ++p){
    const int i   = tid + p * 256;     // 0..511 (float4 units of the 64x32 tile)
    const int row = i >> 3;
    const int c4  = i & 7;
    const f32x4 e0 = *(const f32x4*)(&ebuf[row * 36 + c4 * 4]);
    const f32x4 e1 = *(const f32x4*)(&ebuf[(64 + row) * 36 + c4 * 4]);
    f32x4 o;
    #pragma unroll
    for (int e = 0; e < 4; ++e) o[e] = -(e0[e] + e1[e]);
    *(f32x4*)(&out[(size_t)(r0 + row) * 256 + s0 + c4 * 4]) = o;
  }
}

extern "C" void kernel_launch(void* const* d_in, const int* in_sizes, int n_in,
                              void* d_out, int out_size, void* d_ws, size_t ws_size,
                              hipStream_t stream){
  const float* V = (const float*)d_in[2];   // back_VF  (pre_VF/pre_AF unused by reference)
  const float* A = (const float*)d_in[3];   // back_AF
  float* out = (float*)d_out;
  float* ivn = (float*)((char*)d_ws + IVN_OFF);
  float* icn = (float*)((char*)d_ws + ICN_OFF);
  float* csq = (float*)((char*)d_ws + CSQ_OFF);
  unsigned char* mats = (unsigned char*)((char*)d_ws + MATS_OFF);

  cast_ns_k<<<dim3(8, 32, 2), 256, 0, stream>>>(V, A, mats, csq);
  nreduce_k<<<dim3(32, 2), 256, 0, stream>>>(csq, ivn, icn);
  gemm_both_k<<<dim3(8, 128), 256, 0, stream>>>(mats, ivn, icn, out);
}

// Round 13
// 117.515 us; speedup vs baseline: 1.1387x; 1.0380x over previous
//
#include <hip/hip_runtime.h>
#include <cstdint>

// Problem constants: B=32, T=D=256, rows R = B*T = 8192, K = 256.
#define R_TOT 8192
#define KD    256
#define SLOT  ((size_t)R_TOT * KD)            // bytes per fp8 image (2,097,152)
// ws layout (bytes):  total ~4.8 MB
#define IVN_OFF  0                            // 64 f32: 1/frobenius-norm [ten][j]
#define ICN_OFF  256                          // 2*8192 f32: 1/col-norm [ten][j][s]
#define CSQ_OFF  (ICN_OFF + 65536)            // 8 tc-partials x 2*8192 f32 = 512 KB
#define MATS_OFF (CSQ_OFF + 524288)           // 2 fp8 images (Vq, Aq), swizzled, 4 MB

typedef float f32x4 __attribute__((ext_vector_type(4)));
typedef int   i32x4 __attribute__((ext_vector_type(4)));
typedef int   i32x8 __attribute__((ext_vector_type(8)));   // 32 fp8 = one MX MFMA operand

__device__ __forceinline__ void glds16(const void* g, void* l){
  __builtin_amdgcn_global_load_lds((const __attribute__((address_space(1))) uint32_t*)g,
                                   (__attribute__((address_space(3))) uint32_t*)l, 16, 0, 0);
}

// Image layout (R11-verbatim): plain k-order rows (256 B per image row r), 16B
// chunk c (k in [c*16, c*16+16)) stored at 16B slot c ^ (r & 15). XOR swizzle
// keeps MFMA-layout ds_read_b128 conflict-free (verified R7-R11, 65k conflicts).
__global__ void cast_ns_k(const float* __restrict__ V, const float* __restrict__ A,
                          unsigned char* __restrict__ mats, float* __restrict__ csq){
  const int tc = blockIdx.x, j = blockIdx.y, ten = blockIdx.z;
  const int tid = threadIdx.x;
  const int g    = tid & 31;                 // d-chunk of 8 floats = 8 fp8 bytes
  const int tsub = tid >> 5;                 // 0..7
  const int c    = g >> 1;                   // 16B chunk index 0..15
  const int half = g & 1;                    // which 8B half of the chunk
  const float* X = (ten ? A : V) + (size_t)j * 65536;
  unsigned char* M = mats + (size_t)ten * SLOT + (size_t)j * 65536;
  float cs[8];
  #pragma unroll
  for (int e = 0; e < 8; ++e) cs[e] = 0.f;
  #pragma unroll
  for (int tt = 0; tt < 4; ++tt){
    const int t = tc * 32 + tt * 8 + tsub;
    const float4 p0 = *(const float4*)(X + t * 256 + g * 8);
    const float4 p1 = *(const float4*)(X + t * 256 + g * 8 + 4);
    cs[0] += p0.x * p0.x; cs[1] += p0.y * p0.y; cs[2] += p0.z * p0.z; cs[3] += p0.w * p0.w;
    cs[4] += p1.x * p1.x; cs[5] += p1.y * p1.y; cs[6] += p1.z * p1.z; cs[7] += p1.w * p1.w;
    int d0 = __builtin_amdgcn_cvt_pk_fp8_f32(p0.x, p0.y, 0, false);
    d0     = __builtin_amdgcn_cvt_pk_fp8_f32(p0.z, p0.w, d0, true);
    int d1 = __builtin_amdgcn_cvt_pk_fp8_f32(p1.x, p1.y, 0, false);
    d1     = __builtin_amdgcn_cvt_pk_fp8_f32(p1.z, p1.w, d1, true);
    int2 o; o.x = d0; o.y = d1;
    *(int2*)(M + (size_t)t * 256 + (((c ^ (t & 15)) << 4) | (half << 3))) = o;
  }
  __shared__ float red[8][256];
  #pragma unroll
  for (int e = 0; e < 8; ++e) red[tsub][g * 8 + e] = cs[e];
  __syncthreads();
  float s = 0.f;
  #pragma unroll
  for (int gg = 0; gg < 8; ++gg) s += red[gg][tid];
  csq[(size_t)((tc * 2 + ten) * 32 + j) * 256 + tid] = s;
}

// Finish norms: sum 8 tc-partials; icn = rsqrt, ivn = rsqrt of row-sum. Grid (32, 2).
__global__ void nreduce_k(const float* __restrict__ csq, float* __restrict__ ivn,
                          float* __restrict__ icn){
  const int j = blockIdx.x, ten = blockIdx.y, s = threadIdx.x;
  float c = 0.f;
  #pragma unroll
  for (int tc = 0; tc < 8; ++tc)
    c += csq[(size_t)((tc * 2 + ten) * 32 + j) * 256 + s];
  icn[ten * 8192 + j * 256 + s] = rsqrtf(c + 1e-18f);
  __shared__ float red[256];
  red[s] = c; __syncthreads();
  for (int off = 128; off > 0; off >>= 1){
    if (s < off) red[s] += red[s + off];
    __syncthreads();
  }
  if (s == 0) ivn[ten * 32 + j] = rsqrtf(red[0] + 1e-18f);
}

// v13 = v11 structure + EXPLICIT waitcnt discipline (v12's NaN = iter-0 preload
// race once the incidental drains were removed; no compiler glds->ds_read dep).
//  - pre-loop: s_waitcnt vmcnt(0) lgkmcnt(0) -> preload + csc table guaranteed.
//  - per iter: prefetch jj+1 FIRST, then s_waitcnt vmcnt(4): waits only for the
//    PREVIOUS iteration's glds (aged ~1 iter, free); current 4 stay in flight.
//    Last iter (no prefetch): vmcnt(0).
//  - csc from wave-private LDS table (no global load in the vmcnt queue).
__global__ __launch_bounds__(256, 4) void gemm_both_k(const unsigned char* __restrict__ mats,
                                                      const float* __restrict__ ivn,
                                                      const float* __restrict__ icn,
                                                      float* __restrict__ out){
  __shared__ __align__(16) char smem[40960];  // [0,32K): 4 waves x 2 x 4KB dbuf; [32K,40K): csc
  const int tid  = threadIdx.x;
  const int lane = tid & 63;
  const int w    = tid >> 6;
  const int dir  = w >> 1;              // waves 0,1 -> dir0; 2,3 -> dir1
  const int wn   = (w & 1) * 16;        // wave col slice in 32-col block tile
  const int lm   = lane & 15;
  const int kh   = lane >> 4;           // 0..3 (k-quad: k in [kh*32, kh*32+32) per K-half)
  const int s0   = blockIdx.x * 32;
  const int rb   = blockIdx.y;
  const int r0   = rb * 64;
  const int ib   = rb >> 2;             // batch index of this row tile (excluded diagonal)

  // dir0: rows Vq (scale 1/|V_i|F), cols Aq (scale 1/colnorm A); dir1 swapped.
  const unsigned char* rowmat = mats + (size_t)dir * SLOT;
  const unsigned char* colmat = mats + (size_t)(1 - dir) * SLOT;
  const float sivn = ivn[dir * 32 + ib] * 1.44269504088896340736f;  // * log2(e)

  // Per-wave csc table: csc[j][lm] = sivn * icn_col[j*256 + lm], all 32 j.
  float* cscw = (float*)(smem + 32768) + w * 512;
  {
    const float* ibase = icn + (size_t)(1 - dir) * 8192 + s0 + wn;
    #pragma unroll
    for (int jx = 0; jx < 8; ++jx){
      const int j = kh * 8 + jx;
      cscw[j * 16 + lm] = sivn * ibase[j * 256 + lm];
    }
  }

  // A-fragments: all 64 rows of this wave's dir; K-half t, 16B unit u at slot
  // (t*8 + kh*2 + u) ^ lm. 64 VGPRs.
  i32x8 afr[4][2];                      // [mi][K-half]
  #pragma unroll
  for (int mi = 0; mi < 4; ++mi){
    const unsigned char* rp = rowmat + (size_t)(r0 + mi * 16 + lm) * 256;
    #pragma unroll
    for (int t = 0; t < 2; ++t){
      i32x4 lo = *(const i32x4*)(rp + ((((t << 3) | (kh << 1) | 0) ^ lm) << 4));
      i32x4 hi = *(const i32x4*)(rp + ((((t << 3) | (kh << 1) | 1) ^ lm) << 4));
      afr[mi][t] = i32x8{lo.x, lo.y, lo.z, lo.w, hi.x, hi.y, hi.z, hi.w};
    }
  }
  #pragma unroll
  for (int mi = 0; mi < 4; ++mi)
    #pragma unroll
    for (int t = 0; t < 2; ++t)
      asm volatile("" : "+v"(afr[mi][t]));

  // Wave-private LDS region; j-invariant ds_read offsets (row-in-slice == lm).
  char* wbase = smem + w * 8192;
  int ad[2][2];                         // [K-half][16B unit]
  #pragma unroll
  for (int t = 0; t < 2; ++t)
    #pragma unroll
    for (int u = 0; u < 2; ++u)
      ad[t][u] = lm * 256 + ((((t << 3) | (kh << 1) | u) ^ lm) << 4);
  const int lo16 = lane * 16;           // lane offset within a 1KB chunk-group

  f32x4 acc[4];
  #pragma unroll
  for (int mi = 0; mi < 4; ++mi)
    acc[mi] = f32x4{0.f, 0.f, 0.f, 0.f};

  // Preload j(0) into phase 0 (4KB = 4 chunk-groups, 1 glds16 per lane each).
  {
    const int j0 = (ib == 0) ? 1 : 0;
    const unsigned char* src = colmat + ((size_t)j0 * 256 + s0 + wn) * 256;
    #pragma unroll
    for (int c = 0; c < 4; ++c)
      glds16(src + c * 1024 + lo16, wbase + c * 1024 + lo16);
  }
  // Guarantee preload DMA + csc table writes are visible before iteration 0.
  asm volatile("s_waitcnt vmcnt(0) lgkmcnt(0)" ::: "memory");

  for (int jj = 0; jj < 31; ++jj){
    const int j = jj + (jj >= ib ? 1 : 0);

    // Prefetch jj+1 into the other phase, THEN wait for the PREVIOUS iter's
    // glds only (vmcnt(4): 4 newest = the ones just issued, allowed in flight).
    if (jj < 30){
      const int jn = (jj + 1) + ((jj + 1) >= ib ? 1 : 0);
      const unsigned char* src = colmat + ((size_t)jn * 256 + s0 + wn) * 256;
      char* dst = wbase + (((jj + 1) & 1) << 12);
      #pragma unroll
      for (int c = 0; c < 4; ++c)
        glds16(src + c * 1024 + lo16, dst + c * 1024 + lo16);
      asm volatile("s_waitcnt vmcnt(4)" ::: "memory");
    } else {
      asm volatile("s_waitcnt vmcnt(0)" ::: "memory");
    }

    const char* rbuf = wbase + ((jj & 1) << 12);
    i32x4 lo0 = *(const i32x4*)(rbuf + ad[0][0]);
    i32x4 hi0 = *(const i32x4*)(rbuf + ad[0][1]);
    i32x4 lo1 = *(const i32x4*)(rbuf + ad[1][0]);
    i32x4 hi1 = *(const i32x4*)(rbuf + ad[1][1]);
    const float csc = cscw[j * 16 + lm];        // LDS, no vmcnt involvement

    i32x8 b[2];
    b[0] = i32x8{lo0.x, lo0.y, lo0.z, lo0.w, hi0.x, hi0.y, hi0.z, hi0.w};
    b[1] = i32x8{lo1.x, lo1.y, lo1.z, lo1.w, hi1.x, hi1.y, hi1.z, hi1.w};

    f32x4 S[4];
    #pragma unroll
    for (int mi = 0; mi < 4; ++mi)
      S[mi] = f32x4{0.f, 0.f, 0.f, 0.f};
    #pragma unroll
    for (int t = 0; t < 2; ++t){
      S[0] = __builtin_amdgcn_mfma_scale_f32_16x16x128_f8f6f4(afr[0][t], b[t], S[0], 0, 0, 0, 127, 0, 127);
      S[1] = __builtin_amdgcn_mfma_scale_f32_16x16x128_f8f6f4(afr[1][t], b[t], S[1], 0, 0, 0, 127, 0, 127);
      S[2] = __builtin_amdgcn_mfma_scale_f32_16x16x128_f8f6f4(afr[2][t], b[t], S[2], 0, 0, 0, 127, 0, 127);
      S[3] = __builtin_amdgcn_mfma_scale_f32_16x16x128_f8f6f4(afr[3][t], b[t], S[3], 0, 0, 0, 127, 0, 127);
    }
    #pragma unroll
    for (int mi = 0; mi < 4; ++mi)
      #pragma unroll
      for (int r = 0; r < 4; ++r)
        acc[mi][r] += __builtin_amdgcn_exp2f(S[mi][r] * csc);
    // NO __syncthreads in the K-loop.
  }

  // Epilogue: per-dir log1p into LDS ([2][64][36] f32 = 18KB), combine, coalesced store.
  // C/D layout: col = lane&15, row = (lane>>4)*4 + reg (shape-determined, incl. f8f6f4).
  __syncthreads();                      // all waves' loop reads done (vmcnt drained above)
  float* ebuf = (float*)smem;
  #pragma unroll
  for (int mi = 0; mi < 4; ++mi){
    const int n = wn + lm;
    #pragma unroll
    for (int r = 0; r < 4; ++r){
      const int m = mi * 16 + (kh << 2) + r;
      ebuf[(dir * 64 + m) * 36 + n] = __logf(1.f + acc[mi][r]);
    }
  }
  __syncthreads();
  #pragma unroll
  for (int p = 0; p < 2; ++p){
    const int i   = tid + p * 256;     // 0..511 (float4 units of the 64x32 tile)
    const int row = i >> 3;
    const int c4  = i & 7;
    const f32x4 e0 = *(const f32x4*)(&ebuf[row * 36 + c4 * 4]);
    const f32x4 e1 = *(const f32x4*)(&ebuf[(64 + row) * 36 + c4 * 4]);
    f32x4 o;
    #pragma unroll
    for (int e = 0; e < 4; ++e) o[e] = -(e0[e] + e1[e]);
    *(f32x4*)(&out[(size_t)(r0 + row) * 256 + s0 + c4 * 4]) = o;
  }
}

extern "C" void kernel_launch(void* const* d_in, const int* in_sizes, int n_in,
                              void* d_out, int out_size, void* d_ws, size_t ws_size,
                              hipStream_t stream){
  const float* V = (const float*)d_in[2];   // back_VF  (pre_VF/pre_AF unused by reference)
  const float* A = (const float*)d_in[3];   // back_AF
  float* out = (float*)d_out;
  float* ivn = (float*)((char*)d_ws + IVN_OFF);
  float* icn = (float*)((char*)d_ws + ICN_OFF);
  float* csq = (float*)((char*)d_ws + CSQ_OFF);
  unsigned char* mats = (unsigned char*)((char*)d_ws + MATS_OFF);

  cast_ns_k<<<dim3(8, 32, 2), 256, 0, stream>>>(V, A, mats, csq);
  nreduce_k<<<dim3(32, 2), 256, 0, stream>>>(csq, ivn, icn);
  gemm_both_k<<<dim3(8, 128), 256, 0, stream>>>(mats, ivn, icn, out);
}